// Round 2
// baseline (2750.816 us; speedup 1.0000x reference)
//
#include <hip/hip_runtime.h>
#include <hip/hip_bf16.h>

// ByteNet decoder, fast-WaveNet incremental decoding.
// Constants from the reference:
#define NUM_LABELS 64
#define ENC_DIM 256
#define CC 128
#define C2 256
#define OUT_DIM 512
#define NLAYERS 5
#define RF 63
#define MAX_T 48
#define BATCH 8
#define T_ENC 64
#define LAB_PAD 0
#define LAB_START 5
#define LAB_STOP 6

// ---------------------------------------------------------------------------
// Kernel A: precompute E2[l] = embed[l]@w_in + b_in   (64 x 256)
//           encp[b,k] = enc[b,:,k]@w_enc + b_enc      (8 x 48 x 256)
// blocks 0..63 -> E2 rows; blocks 64..447 -> encp rows.
// ---------------------------------------------------------------------------
__global__ __launch_bounds__(256) void pre_kernel(
    const float* __restrict__ enc,    // (8,256,64)
    const float* __restrict__ embed,  // (64,256)
    const float* __restrict__ w_in,   // (256,256)
    const float* __restrict__ b_in,   // (256)
    const float* __restrict__ w_enc,  // (256,256)
    const float* __restrict__ b_enc,  // (256)
    float* __restrict__ E2,           // (64,256)
    float* __restrict__ encp)         // (8,48,256)
{
    const int t = threadIdx.x;
    const int blk = blockIdx.x;
    if (blk < NUM_LABELS) {
        float acc = b_in[t];
        const float* e = embed + blk * C2;
        for (int j = 0; j < C2; ++j) acc += e[j] * w_in[j * C2 + t];
        E2[blk * C2 + t] = acc;
    } else {
        const int idx = blk - NUM_LABELS;     // 0..383
        const int b = idx / MAX_T;
        const int k = idx % MAX_T;
        float acc = b_enc[t];
        const float* ecol = enc + b * ENC_DIM * T_ENC + k;  // stride T_ENC over channels
        for (int c = 0; c < ENC_DIM; ++c) acc += ecol[c * T_ENC] * w_enc[c * C2 + t];
        encp[idx * C2 + t] = acc;
    }
}

// ---------------------------------------------------------------------------
// Kernel B: uniform prefix chain. All prefix positions (labels=PAD, enc=0)
// share x0 = embed[PAD]@w_in + b_in + b_enc; per layer the conv taps are all
// equal so conv = h0 @ (wd[0]+wd[1]+wd[2]) + bd. Stores h0[i] (5 x 128).
// ---------------------------------------------------------------------------
__global__ __launch_bounds__(256) void prefix_kernel(
    const float* __restrict__ embed, const float* __restrict__ w_in,
    const float* __restrict__ b_in,  const float* __restrict__ b_enc,
    const float* __restrict__ w1,    const float* __restrict__ b1,
    const float* __restrict__ wd,    const float* __restrict__ bd,
    const float* __restrict__ w2,    const float* __restrict__ b2,
    float* __restrict__ h0out)       // (5,128)
{
    const int t = threadIdx.x;
    __shared__ float x[C2];
    __shared__ float r[C2];
    __shared__ float h[CC];
    __shared__ float hr[CC];

    {
        float acc = b_in[t] + b_enc[t];
        const float* e = embed + LAB_PAD * C2;
        for (int j = 0; j < C2; ++j) acc += e[j] * w_in[j * C2 + t];
        x[t] = acc;
    }
    __syncthreads();

    for (int i = 0; i < NLAYERS; ++i) {
        r[t] = fmaxf(x[t], 0.f);
        __syncthreads();
        if (t < CC) {
            float a = b1[i * CC + t];
            const float* W = w1 + (i * C2) * CC + t;
            for (int j = 0; j < C2; ++j) a += r[j] * W[j * CC];
            float hv = fmaxf(a, 0.f);
            h[t] = hv;
            h0out[i * CC + t] = hv;
        }
        __syncthreads();
        if (t < CC) {
            float a = bd[i * CC + t];
            const float* W0 = wd + ((i * 3 + 0) * CC) * CC + t;
            const float* W1 = wd + ((i * 3 + 1) * CC) * CC + t;
            const float* W2 = wd + ((i * 3 + 2) * CC) * CC + t;
            for (int c = 0; c < CC; ++c) {
                float wsum = W0[c * CC] + W1[c * CC] + W2[c * CC];
                a += h[c] * wsum;
            }
            hr[t] = fmaxf(a, 0.f);
        }
        __syncthreads();
        {
            float a = b2[i * C2 + t];
            const float* W = w2 + (i * CC) * C2 + t;
            for (int c = 0; c < CC; ++c) a += hr[c] * W[c * C2];
            x[t] += a;
        }
        __syncthreads();
    }
}

// ---------------------------------------------------------------------------
// Kernel C: the 48-step sequential decode. One block per batch element,
// no inter-block communication. Ring buffers for conv history in LDS.
// ---------------------------------------------------------------------------
__global__ __launch_bounds__(256) void decode_kernel(
    const float* __restrict__ w1,   // (5,256,128)
    const float* __restrict__ b1,   // (5,128)
    const float* __restrict__ wd,   // (5,3,128,128)
    const float* __restrict__ bd,   // (5,128)
    const float* __restrict__ w2,   // (5,128,256)
    const float* __restrict__ b2,   // (5,256)
    const float* __restrict__ wo1,  // (256,512)
    const float* __restrict__ bo1,  // (512)
    const float* __restrict__ wo2,  // (512,64)
    const float* __restrict__ bo2,  // (64)
    const float* __restrict__ E2,   // (64,256)
    const float* __restrict__ encp, // (8,48,256)
    const float* __restrict__ h0g,  // (5,128)
    float* __restrict__ out)        // logits (8,64,48) then lengths (8)
{
    const int b = blockIdx.x;
    const int t = threadIdx.x;

    // ring sizes 2d+1 for d = 1,2,4,8,16
    __shared__ float ring0[3 * CC];
    __shared__ float ring1[5 * CC];
    __shared__ float ring2[9 * CC];
    __shared__ float ring3[17 * CC];
    __shared__ float ring4[33 * CC];
    __shared__ float h0s[NLAYERS * CC];
    __shared__ float x[C2];
    __shared__ float r[C2];
    __shared__ float h[CC];
    __shared__ float hr[CC];
    __shared__ float part[256];
    __shared__ float u[OUT_DIM];
    __shared__ float lg[NUM_LABELS];
    __shared__ int s_lab;
    __shared__ int s_stop;

    float* rings[NLAYERS] = { ring0, ring1, ring2, ring3, ring4 };
    const int rsz[NLAYERS] = { 3, 5, 9, 17, 33 };

    for (int idx = t; idx < NLAYERS * CC; idx += 256) h0s[idx] = h0g[idx];
    if (t == 0) { s_lab = LAB_START; s_stop = MAX_T; }
    __syncthreads();

    for (int k = 0; k < MAX_T; ++k) {
        const int lab = s_lab;
        x[t] = E2[lab * C2 + t] + encp[(b * MAX_T + k) * C2 + t];
        r[t] = fmaxf(x[t], 0.f);
        __syncthreads();

        for (int i = 0; i < NLAYERS; ++i) {
            const int d = 1 << i;
            // ---- h = relu(relu(x) @ w1 + b1), split: 2 threads per output ----
            {
                const int c = t & (CC - 1);
                const int half = t >> 7;           // 0 or 1
                float a = 0.f;
                const float* W = w1 + (i * C2 + half * CC) * CC + c;
                const float* rr = r + half * CC;
                for (int j = 0; j < CC; ++j) a += rr[j] * W[j * CC];
                part[t] = a;
            }
            __syncthreads();
            if (t < CC) {
                float hv = fmaxf(part[t] + part[t + CC] + b1[i * CC + t], 0.f);
                h[t] = hv;
                rings[i][(k % rsz[i]) * CC + t] = hv;   // current position into ring
            }
            __syncthreads();
            // ---- dilated conv: taps at k (h), k-d, k-2d (rings or h0) ----
            {
                const int c = t & (CC - 1);
                const int half = t >> 7;
                const float* tap1 = (k >= d)     ? &rings[i][((k - d)     % rsz[i]) * CC] : &h0s[i * CC];
                const float* tap0 = (k >= 2 * d) ? &rings[i][((k - 2 * d) % rsz[i]) * CC] : &h0s[i * CC];
                const float* W0 = wd + ((i * 3 + 0) * CC) * CC + c;
                const float* W1 = wd + ((i * 3 + 1) * CC) * CC + c;
                const float* W2 = wd + ((i * 3 + 2) * CC) * CC + c;
                float a = 0.f;
                const int c0 = half * 64, c1 = c0 + 64;
                for (int cc = c0; cc < c1; ++cc) {
                    a += h[cc]    * W2[cc * CC];
                    a += tap1[cc] * W1[cc * CC];
                    a += tap0[cc] * W0[cc * CC];
                }
                part[t] = a;
            }
            __syncthreads();
            if (t < CC) {
                hr[t] = fmaxf(part[t] + part[t + CC] + bd[i * CC + t], 0.f);
            }
            __syncthreads();
            // ---- x += relu(conv) @ w2 + b2 ; refresh r ----
            {
                float a = b2[i * C2 + t];
                const float* W = w2 + (i * CC) * C2 + t;
                for (int c = 0; c < CC; ++c) a += hr[c] * W[c * C2];
                float xv = x[t] + a;
                x[t] = xv;
                r[t] = fmaxf(xv, 0.f);
            }
            __syncthreads();
        }

        // ---- head: u = relu(x @ wo1 + bo1)  (512), 2 outputs/thread ----
        // NOTE: reference applies w_o1 to the residual stream x DIRECTLY
        // (relu comes after the matmul), not to relu(x).
        for (int rep = 0; rep < 2; ++rep) {
            const int o = t + rep * 256;
            float a = bo1[o];
            const float* W = wo1 + o;
            for (int j = 0; j < C2; ++j) a += x[j] * W[j * OUT_DIM];
            u[o] = fmaxf(a, 0.f);
        }
        __syncthreads();
        // ---- logits = u @ wo2 + bo2  (64), 4 threads per output ----
        {
            const int l = t & (NUM_LABELS - 1);
            const int q = t >> 6;                 // 0..3
            float a = 0.f;
            const float* W = wo2 + l;
            const int o0 = q * 128, o1 = o0 + 128;
            for (int o = o0; o < o1; ++o) a += u[o] * W[o * NUM_LABELS];
            part[t] = a;
        }
        __syncthreads();
        if (t < NUM_LABELS) {
            float a = part[t] + part[t + 64] + part[t + 128] + part[t + 192] + bo2[t];
            lg[t] = a;
            out[(b * NUM_LABELS + t) * MAX_T + k] = a;
        }
        __syncthreads();
        // ---- argmax (first max index), feedback ----
        if (t == 0) {
            float best = lg[0];
            int bi = 0;
            for (int l = 1; l < NUM_LABELS; ++l) {
                if (lg[l] > best) { best = lg[l]; bi = l; }
            }
            s_lab = bi;
            if (bi == LAB_STOP && s_stop == MAX_T) s_stop = k;
        }
        __syncthreads();
    }

    if (t == 0) {
        out[BATCH * NUM_LABELS * MAX_T + b] = (float)s_stop;
    }
}

// ---------------------------------------------------------------------------
extern "C" void kernel_launch(void* const* d_in, const int* in_sizes, int n_in,
                              void* d_out, int out_size, void* d_ws, size_t ws_size,
                              hipStream_t stream) {
    const float* enc   = (const float*)d_in[0];
    const float* embed = (const float*)d_in[1];
    const float* w_in  = (const float*)d_in[2];
    const float* b_in  = (const float*)d_in[3];
    const float* w_enc = (const float*)d_in[4];
    const float* b_enc = (const float*)d_in[5];
    const float* w1    = (const float*)d_in[6];
    const float* b1    = (const float*)d_in[7];
    const float* wd    = (const float*)d_in[8];
    const float* bd    = (const float*)d_in[9];
    const float* w2    = (const float*)d_in[10];
    const float* b2    = (const float*)d_in[11];
    const float* wo1   = (const float*)d_in[12];
    const float* bo1   = (const float*)d_in[13];
    const float* wo2   = (const float*)d_in[14];
    const float* bo2   = (const float*)d_in[15];
    float* out = (float*)d_out;
    float* ws  = (float*)d_ws;

    float* E2   = ws;                 // 64*256   = 16384 floats
    float* encp = ws + 16384;         // 8*48*256 = 98304 floats
    float* h0   = ws + 16384 + 98304; // 5*128    = 640 floats

    pre_kernel<<<NUM_LABELS + BATCH * MAX_T, 256, 0, stream>>>(
        enc, embed, w_in, b_in, w_enc, b_enc, E2, encp);
    prefix_kernel<<<1, 256, 0, stream>>>(
        embed, w_in, b_in, b_enc, w1, b1, wd, bd, w2, b2, h0);
    decode_kernel<<<BATCH, 256, 0, stream>>>(
        w1, b1, wd, bd, w2, b2, wo1, bo1, wo2, bo2, E2, encp, h0, out);
}